// Round 7
// baseline (429.855 us; speedup 1.0000x reference)
//
#include <hip/hip_runtime.h>

#define BN 32768
#define IN 512
#define NE 8
#define NH 128
#define MO 256
#define RT 128    // rows per expert tile
#define KC1 32    // stage-1 k-chunk
#define KC2 16    // stage-2 k-chunk
#define XS_S 36   // xs row stride (dwords)

// ---------------- gating: 64 rows/block, k-split 4 (ks wave-uniform) --------
// f64 accumulation so top-2 ranking matches np at near-ties (proven r1-r6).
__global__ __launch_bounds__(256) void gate_kernel(
    const float* __restrict__ x, const float* __restrict__ wg,
    int* __restrict__ gcount, int* __restrict__ gload, float* __restrict__ gimp,
    int* __restrict__ idx_list, float* __restrict__ gate_list,
    float* __restrict__ out, const float* __restrict__ bout)
{
    __shared__ float wgs[IN * NE];          // 16 KB
    __shared__ double prt[4][64][9];        // 18 KB (pad 9 -> writes spread)
    __shared__ int counts_s[NE];
    __shared__ int load_s[NE];
    __shared__ float imp_s[NE];
    __shared__ int base_s[NE];

    int tid = threadIdx.x;
    int row0 = blockIdx.x * 64;

    #pragma unroll
    for (int p = 0; p < 4; ++p)
        ((float4*)wgs)[p * 256 + tid] = ((const float4*)wg)[p * 256 + tid];
    if (tid < NE) { counts_s[tid] = 0; load_s[tid] = 0; imp_s[tid] = 0.f; }
    if (tid < 128) out[(size_t)row0 * 2 + tid] = bout[tid & 1];  // fused init

    int r  = tid & 63;                       // lane = row
    int ks = tid >> 6;                       // wave-uniform k-slice
    const float* xr = x + (size_t)(row0 + r) * IN + ks * 128;

    double acc[NE];
    #pragma unroll
    for (int e = 0; e < NE; ++e) acc[e] = 0.0;
    __syncthreads();

    float4 xv = *(const float4*)xr;          // manual pipeline
    for (int k0 = 0; k0 < 128; k0 += 4) {
        float4 cur = xv;
        if (k0 + 4 < 128) xv = *(const float4*)(xr + k0 + 4);
        float xa[4] = {cur.x, cur.y, cur.z, cur.w};
        #pragma unroll
        for (int j = 0; j < 4; ++j) {
            double xd = (double)xa[j];
            const float* wk = wgs + (ks * 128 + k0 + j) * NE;  // wave-uniform
            float4 wa = *(const float4*)wk;
            float4 wb = *(const float4*)(wk + 4);
            acc[0] += xd * (double)wa.x; acc[1] += xd * (double)wa.y;
            acc[2] += xd * (double)wa.z; acc[3] += xd * (double)wa.w;
            acc[4] += xd * (double)wb.x; acc[5] += xd * (double)wb.y;
            acc[6] += xd * (double)wb.z; acc[7] += xd * (double)wb.w;
        }
    }
    #pragma unroll
    for (int e = 0; e < NE; ++e) prt[ks][r][e] = acc[e];
    __syncthreads();

    int e0 = 0, e1 = 1, p0 = 0, p1 = 0;
    float g0 = 0.f, g1 = 0.f;
    if (tid < 64) {
        double a2[NE];
        #pragma unroll
        for (int e = 0; e < NE; ++e)
            a2[e] = prt[0][tid][e] + prt[1][tid][e]
                  + prt[2][tid][e] + prt[3][tid][e];
        double v0 = a2[0]; e0 = 0;
        #pragma unroll
        for (int e = 1; e < NE; ++e) if (a2[e] > v0) { v0 = a2[e]; e0 = e; }
        e1 = (e0 == 0) ? 1 : 0; double v1 = a2[e1];
        #pragma unroll
        for (int e = 0; e < NE; ++e)
            if (e != e0 && a2[e] > v1) { v1 = a2[e]; e1 = e; }
        float t1 = expf((float)(v1 - v0));
        float s = 1.f + t1;
        g0 = 1.f / s;
        g1 = t1 / s;
        atomicAdd(&imp_s[e0], g0);
        atomicAdd(&imp_s[e1], g1);
        if (g0 > 0.f) atomicAdd(&load_s[e0], 1);
        if (g1 > 0.f) atomicAdd(&load_s[e1], 1);
        p0 = atomicAdd(&counts_s[e0], 1);
        p1 = atomicAdd(&counts_s[e1], 1);
    }
    __syncthreads();
    if (tid < NE) {
        base_s[tid] = atomicAdd(&gcount[tid], counts_s[tid]);
        atomicAdd(&gimp[tid], imp_s[tid]);
        atomicAdd(&gload[tid], load_s[tid]);
    }
    __syncthreads();
    if (tid < 64) {
        int row = row0 + tid;
        idx_list[e0 * BN + base_s[e0] + p0] = row;
        gate_list[e0 * BN + base_s[e0] + p0] = g0;
        idx_list[e1 * BN + base_s[e1] + p1] = row;
        gate_list[e1 * BN + base_s[e1] + p1] = g1;
    }
}

// ---------------- loss ----------------
__global__ void loss_kernel(const float* __restrict__ gimp, const int* __restrict__ gload,
                            float* __restrict__ out) {
    if (threadIdx.x == 0 && blockIdx.x == 0) {
        float mi = 0.f, ml = 0.f;
        for (int e = 0; e < NE; ++e) { mi += gimp[e]; ml += (float)gload[e]; }
        mi *= 0.125f; ml *= 0.125f;
        float vi = 0.f, vl = 0.f;
        for (int e = 0; e < NE; ++e) {
            float d = gimp[e] - mi;  vi += d * d;
            float d2 = (float)gload[e] - ml; vl += d2 * d2;
        }
        vi *= (1.f / 7.f); vl *= (1.f / 7.f);
        float loss = (vi / (mi * mi + 1e-10f) + vl / (ml * ml + 1e-10f)) * 0.01f;
        out[BN * 2] = loss;
    }
}

// ---------------- expert: RT=128; 8x8 stage1, 8x16 stage2 -------------------
// Rows per thread strided (ty + 16*i) so each wave's A-reads hit 4 consecutive
// rows (conflict-free). Register double-buffer everywhere (no global_load_lds
// -> no vmcnt(0) barrier drain). amdgpu_waves_per_eu(2,2) pins occupancy at
// 2 blocks/CU (the 80 KB LDS limit) so RA can use ~220 VGPRs WITHOUT spilling.
__global__ __launch_bounds__(256)
__attribute__((amdgpu_waves_per_eu(2, 2)))
void expert_kernel(
    const float* __restrict__ x,
    const float* __restrict__ W1, const float* __restrict__ b1,
    const float* __restrict__ W2, const float* __restrict__ b2,
    const float* __restrict__ Wout,
    const int* __restrict__ gcount,
    const int* __restrict__ idx_list, const float* __restrict__ gate_list,
    float* __restrict__ out)
{
    __shared__ __align__(16) union {
        struct { float xs[RT][XS_S]; float ws1[KC1][NH]; } s1; // 18432+16384
        struct { float hs[RT][NH];   float w2s[KC2][MO]; } s2; // 65536+16384
    } sm;                                                      // union: 81920

    int e = blockIdx.y;
    int cnt = gcount[e];
    int row0 = blockIdx.x * RT;
    if (row0 >= cnt) return;            // uniform exit before any barrier
    int tid = threadIdx.x;
    int tx = tid & 15;                  // col group
    int ty = tid >> 4;                  // base row; thread rows = ty + 16*i

    int sr = tid >> 1, sh = tid & 1;    // X staging: 2 threads/row
    int sgi = row0 + sr; if (sgi >= cnt) sgi = cnt - 1;
    const float* xrow = x + (size_t)idx_list[e * BN + sgi] * IN;

    const float* W1e = W1 + (size_t)e * IN * NH;
    const float* W2e = W2 + (size_t)e * NH * MO;

    // ---- stage 1: H[128x128] = relu(X @ W1 + b1), 8x8 micro-tile ----
    float c1[8][8] = {};
    float4 px[4], pw[4];
    #pragma unroll
    for (int p = 0; p < 4; ++p)
        px[p] = *(const float4*)(xrow + sh * 16 + p * 4);
    #pragma unroll
    for (int p = 0; p < 4; ++p)
        pw[p] = *(const float4*)(W1e + p * 1024 + tid * 4);

    for (int c = 0; c < IN / KC1; ++c) {
        if (c) __syncthreads();                   // prev chunk consumed
        #pragma unroll
        for (int p = 0; p < 4; ++p)
            *(float4*)&sm.s1.xs[sr][sh * 16 + p * 4] = px[p];
        {
            float* l = &sm.s1.ws1[0][0];
            #pragma unroll
            for (int p = 0; p < 4; ++p)
                *(float4*)(l + p * 1024 + tid * 4) = pw[p];
        }
        __syncthreads();                          // publish chunk c
        if (c + 1 < IN / KC1) {                   // reg prefetch (no drain)
            int k0n = (c + 1) * KC1;
            #pragma unroll
            for (int p = 0; p < 4; ++p)
                px[p] = *(const float4*)(xrow + k0n + sh * 16 + p * 4);
            const float* nw = W1e + (size_t)k0n * NH;
            #pragma unroll
            for (int p = 0; p < 4; ++p)
                pw[p] = *(const float4*)(nw + p * 1024 + tid * 4);
        }
        #pragma unroll 2
        for (int kq = 0; kq < KC1 / 4; ++kq) {
            float a[8][4];
            #pragma unroll
            for (int i = 0; i < 8; ++i) {
                float4 av = *(const float4*)&sm.s1.xs[ty + 16 * i][kq * 4];
                a[i][0] = av.x; a[i][1] = av.y; a[i][2] = av.z; a[i][3] = av.w;
            }
            #pragma unroll
            for (int kk = 0; kk < 4; ++kk) {
                float4 blo = *(const float4*)&sm.s1.ws1[kq * 4 + kk][tx * 8];
                float4 bhi = *(const float4*)&sm.s1.ws1[kq * 4 + kk][tx * 8 + 4];
                float bb[8] = {blo.x, blo.y, blo.z, blo.w,
                               bhi.x, bhi.y, bhi.z, bhi.w};
                #pragma unroll
                for (int i = 0; i < 8; ++i)
                    #pragma unroll
                    for (int j = 0; j < 8; ++j)
                        c1[i][j] = fmaf(a[i][kk], bb[j], c1[i][j]);
            }
        }
    }

    // prefetch W2 chunk 0 (flies over the transition barrier)
    float4 pw2[4];
    #pragma unroll
    for (int p = 0; p < 4; ++p)
        pw2[p] = *(const float4*)(W2e + p * 1024 + tid * 4);

    __syncthreads();                              // stage-1 LDS reads done
    {   // relu + b1 -> hs (2-way-free strips)
        float4 qlo = *(const float4*)(b1 + e * NH + tx * 8);
        float4 qhi = *(const float4*)(b1 + e * NH + tx * 8 + 4);
        float bb[8] = {qlo.x, qlo.y, qlo.z, qlo.w, qhi.x, qhi.y, qhi.z, qhi.w};
        #pragma unroll
        for (int i = 0; i < 8; ++i) {
            float4 lo, hi;
            lo.x = fmaxf(c1[i][0] + bb[0], 0.f);
            lo.y = fmaxf(c1[i][1] + bb[1], 0.f);
            lo.z = fmaxf(c1[i][2] + bb[2], 0.f);
            lo.w = fmaxf(c1[i][3] + bb[3], 0.f);
            hi.x = fmaxf(c1[i][4] + bb[4], 0.f);
            hi.y = fmaxf(c1[i][5] + bb[5], 0.f);
            hi.z = fmaxf(c1[i][6] + bb[6], 0.f);
            hi.w = fmaxf(c1[i][7] + bb[7], 0.f);
            *(float4*)&sm.s2.hs[ty + 16 * i][tx * 8]     = lo;
            *(float4*)&sm.s2.hs[ty + 16 * i][tx * 8 + 4] = hi;
        }
    }

    // ---- stage 2: Z[128x256] = H @ W2, 8x16 micro-tile (single pass) ----
    // thread cols: j<8 -> tx*8+j ; j>=8 -> 128+tx*8+(j-8)
    float z[8][16] = {};
    for (int c = 0; c < NH / KC2; ++c) {
        if (c) __syncthreads();                   // prev w2s consumed
        {
            float* l = &sm.s2.w2s[0][0];
            #pragma unroll
            for (int p = 0; p < 4; ++p)
                *(float4*)(l + p * 1024 + tid * 4) = pw2[p];
        }
        __syncthreads();                          // publish hs (c==0) + w2s
        if (c + 1 < NH / KC2) {
            const float* nw = W2e + (size_t)(c + 1) * KC2 * MO;
            #pragma unroll
            for (int p = 0; p < 4; ++p)
                pw2[p] = *(const float4*)(nw + p * 1024 + tid * 4);
        }
        #pragma unroll 2
        for (int kq = 0; kq < KC2 / 4; ++kq) {
            float a[8][4];
            #pragma unroll
            for (int i = 0; i < 8; ++i) {
                float4 av = *(const float4*)&sm.s2.hs[ty + 16 * i][c * KC2 + kq * 4];
                a[i][0] = av.x; a[i][1] = av.y; a[i][2] = av.z; a[i][3] = av.w;
            }
            #pragma unroll
            for (int kk = 0; kk < 4; ++kk) {
                const float* wrow = &sm.s2.w2s[kq * 4 + kk][0];
                float4 b0  = *(const float4*)&wrow[tx * 8];
                float4 b1v = *(const float4*)&wrow[tx * 8 + 4];
                float4 b2v = *(const float4*)&wrow[128 + tx * 8];
                float4 b3v = *(const float4*)&wrow[128 + tx * 8 + 4];
                float bb[16] = {b0.x,  b0.y,  b0.z,  b0.w,
                                b1v.x, b1v.y, b1v.z, b1v.w,
                                b2v.x, b2v.y, b2v.z, b2v.w,
                                b3v.x, b3v.y, b3v.z, b3v.w};
                #pragma unroll
                for (int i = 0; i < 8; ++i)
                    #pragma unroll
                    for (int j = 0; j < 16; ++j)
                        z[i][j] = fmaf(a[i][kk], bb[j], z[i][j]);
            }
        }
    }

    // ---- epilogue: softmax over 256 (16 tx lanes x 16 cols), fused @Wout ----
    float4 za = *(const float4*)(b2 + e * MO + tx * 8);
    float4 zb = *(const float4*)(b2 + e * MO + tx * 8 + 4);
    float4 zc = *(const float4*)(b2 + e * MO + 128 + tx * 8);
    float4 zd = *(const float4*)(b2 + e * MO + 128 + tx * 8 + 4);
    float bz[16] = {za.x, za.y, za.z, za.w, zb.x, zb.y, zb.z, zb.w,
                    zc.x, zc.y, zc.z, zc.w, zd.x, zd.y, zd.z, zd.w};
    const float* wpA = Wout + tx * 16;
    const float* wpB = Wout + 256 + tx * 16;
    float4 qa0 = *(const float4*)wpA,       qa1 = *(const float4*)(wpA + 4);
    float4 qa2 = *(const float4*)(wpA + 8), qa3 = *(const float4*)(wpA + 12);
    float4 qb0 = *(const float4*)wpB,       qb1 = *(const float4*)(wpB + 4);
    float4 qb2 = *(const float4*)(wpB + 8), qb3 = *(const float4*)(wpB + 12);
    float wo0[16] = {qa0.x, qa0.z, qa1.x, qa1.z, qa2.x, qa2.z, qa3.x, qa3.z,
                     qb0.x, qb0.z, qb1.x, qb1.z, qb2.x, qb2.z, qb3.x, qb3.z};
    float wo1[16] = {qa0.y, qa0.w, qa1.y, qa1.w, qa2.y, qa2.w, qa3.y, qa3.w,
                     qb0.y, qb0.w, qb1.y, qb1.w, qb2.y, qb2.w, qb3.y, qb3.w};

    #pragma unroll
    for (int i = 0; i < 8; ++i) {
        float m = -1e30f;
        #pragma unroll
        for (int j = 0; j < 16; ++j) { z[i][j] += bz[j]; m = fmaxf(m, z[i][j]); }
        #pragma unroll
        for (int mk = 1; mk < 16; mk <<= 1) m = fmaxf(m, __shfl_xor(m, mk, 16));
        float s = 0.f, w0 = 0.f, w1 = 0.f;
        #pragma unroll
        for (int j = 0; j < 16; ++j) {
            float t = __expf(z[i][j] - m);
            s += t;
            w0 = fmaf(t, wo0[j], w0);
            w1 = fmaf(t, wo1[j], w1);
        }
        #pragma unroll
        for (int mk = 1; mk < 16; mk <<= 1) {
            s  += __shfl_xor(s,  mk, 16);
            w0 += __shfl_xor(w0, mk, 16);
            w1 += __shfl_xor(w1, mk, 16);
        }
        if (tx == 2 * (i & 7)) {             // one lane per row, spread
            int gi = row0 + ty + 16 * i;
            if (gi < cnt) {
                float g = gate_list[e * BN + gi];
                int brow = idx_list[e * BN + gi];
                float inv = 1.f / s;
                atomicAdd(&out[brow * 2 + 0], g * w0 * inv);
                atomicAdd(&out[brow * 2 + 1], g * w1 * inv);
            }
        }
    }
}

extern "C" void kernel_launch(void* const* d_in, const int* in_sizes, int n_in,
                              void* d_out, int out_size, void* d_ws, size_t ws_size,
                              hipStream_t stream) {
    const float* x    = (const float*)d_in[0];
    // d_in[1] = cat_prop, unused by the reference
    const float* wg   = (const float*)d_in[2];
    const float* W1   = (const float*)d_in[3];
    const float* b1   = (const float*)d_in[4];
    const float* W2   = (const float*)d_in[5];
    const float* b2   = (const float*)d_in[6];
    const float* Wout = (const float*)d_in[7];
    const float* bout = (const float*)d_in[8];
    float* out = (float*)d_out;

    char* ws = (char*)d_ws;
    int*   gcount    = (int*)(ws + 0);
    int*   gload     = (int*)(ws + 32);
    float* gimp      = (float*)(ws + 64);
    int*   idx_list  = (int*)(ws + 128);
    float* gate_list = (float*)(ws + 128 + sizeof(int) * NE * BN);

    hipMemsetAsync(ws, 0, 128, stream);
    gate_kernel<<<BN / 64, 256, 0, stream>>>(x, wg, gcount, gload, gimp,
                                             idx_list, gate_list, out, bout);
    loss_kernel<<<1, 64, 0, stream>>>(gimp, gload, out);
    dim3 eg(BN / RT, NE);
    expert_kernel<<<eg, 256, 0, stream>>>(x, W1, b1, W2, b2, Wout,
                                          gcount, idx_list, gate_list, out);
}